// Round 6
// baseline (310.488 us; speedup 1.0000x reference)
//
#include <hip/hip_runtime.h>
#include <math.h>

#define B_ 2
#define F_ 128
#define N_ 192
#define S_ 192
#define NS_ (N_ * S_)          // 36864
#define LOG2E 1.4426950408889634f
#define NBLK 512
#define NTHR 384
#define TOTAL_A 640            // items 0..383 projection (b,n); 384..639 rowsum
#define TOTAL_B 512            // (bh, it3) R=3 attention
#define TOTAL_C 512            // (bh, d) expansion planes

#if defined(__has_builtin)
#if __has_builtin(__builtin_amdgcn_exp2f)
#define EXP2(x) __builtin_amdgcn_exp2f(x)
#else
#define EXP2(x) exp2f(x)
#endif
#else
#define EXP2(x) exp2f(x)
#endif

// Workspace layout (float offsets) — no counters in ws (ws is poisoned).
#define OFF_PART 0                          // [b*128+f] 256 floats, X row sums
#define OFF_PE   256                        // float2 [bh][i][s] = (exp2(p), exp2(.2p)); masked -> (0,0)
#define OFF_QD   (OFF_PE + 8 * NS_ * 2)     // float [bh][s][j] raw dst logits (log2 domain)
#define OFF_QT   (OFF_QD + 8 * NS_)         // float [bh][j][s]
#define OFF_ACC  (OFF_QT + 8 * NS_)         // float [bh][i][s] pre-expansion result

// Persistent counters: zero-initialized at module load; the LAST block to exit
// each run resets them to 0. Runs are stream-serialized (graph replays), so
// the invariant "all counters are 0 at kernel entry" holds for every replay.
// 0:qA 1:doneA 2:qB 3:doneB 4:qC 5:exitCnt
__device__ int g_ctr[8];

#define AGENT __HIP_MEMORY_SCOPE_AGENT

__device__ __forceinline__ int grabItem(int* q, int* item_sh, int t) {
    if (t == 0)
        *item_sh = __hip_atomic_fetch_add(q, 1, __ATOMIC_RELAXED, AGENT);
    __syncthreads();
    return *item_sh;
}

__device__ __forceinline__ void markDone(int* d, int t) {
    __syncthreads();                        // all lanes finished the item's work
    if (t == 0) {
        __threadfence();
        __hip_atomic_fetch_add(d, 1, __ATOMIC_RELEASE, AGENT);
    }
    __syncthreads();                        // protects shared-buffer reuse next item
}

__device__ __forceinline__ void waitDone(int* d, int target, int t) {
    if (t == 0) {
        int guard = 0;
        while (__hip_atomic_load(d, __ATOMIC_ACQUIRE, AGENT) < target &&
               ++guard < (1 << 21))          // ~0.5s failsafe: fail visibly, not hang
            __builtin_amdgcn_s_sleep(8);
        __threadfence();
    }
    __syncthreads();
}

__global__ __launch_bounds__(NTHR, 3) void kFused(const float* __restrict__ X,
                                                  const int* __restrict__ A,
                                                  const float* __restrict__ W_lin,
                                                  const float* __restrict__ b_lin,
                                                  const float* __restrict__ W_attn,
                                                  const float* __restrict__ b_attn,
                                                  float* __restrict__ ws,
                                                  float* __restrict__ out) {
    __shared__ float wslf[512], wdlf[512], csh[4], cdh[4];
    __shared__ float red1[2 * 192 * 9];     // [fq][s][8 +1 pad]
    __shared__ float4 peA4[192];
    __shared__ float2 peB2[192];
    __shared__ float zpart[2 * 3 * 192];    // [sq][r][j]
    __shared__ float4 zr4[192];             // [j] = (zr_r0, zr_r1, zr_r2, -)
    __shared__ float accp[2 * 3 * 192];     // [jt][r][s]
    __shared__ float sg_red[8];
    __shared__ int item_sh;
    int t = threadIdx.x;

    // ---- W prologue (every block; needed by projection items; cheap) ----
    {
        const float4* wa4 = (const float4*)W_attn;
        for (int c = t; c < 512; c += NTHR) {
            int f = c >> 2, h = c & 3;
            const float4* wl = (const float4*)(W_lin + f * 256 + h * 64);
            float as = 0.f, ad = 0.f;
#pragma unroll
            for (int qq = 0; qq < 16; qq++) {
                float4 w = wl[qq], a1 = wa4[qq], a2 = wa4[16 + qq];
                as += w.x * a1.x + w.y * a1.y + w.z * a1.z + w.w * a1.w;
                ad += w.x * a2.x + w.y * a2.y + w.z * a2.z + w.w * a2.w;
            }
            wslf[c] = as * LOG2E;
            wdlf[c] = ad * LOG2E;
        }
        if (t < 8) {
            int h = t & 3;
            const float* bl = b_lin + h * 64;
            const float* wa = W_attn + ((t >= 4) ? 64 : 0);
            float c = 0.f;
            for (int d = 0; d < 64; d++) c += bl[d] * wa[d];
            if (t < 4) csh[h] = (c + b_attn[0]) * LOG2E;
            else cdh[h] = c * LOG2E;
        }
        __syncthreads();
    }

    // ================= Phase A queue: projection + rowsums =================
    for (;;) {
        int v = grabItem(&g_ctr[0], &item_sh, t);
        if (v >= TOTAL_A) break;
        if (v < 384) {
            // ---- projection for (b, n), full s range ----
            int n = v % 192, b = v / 192;
            int fq = t / 192, sl = t % 192; // f halves of 64, s full
            float aS[4] = {0, 0, 0, 0}, aD[4] = {0, 0, 0, 0};
            const float* xp = X + (size_t)(b * F_) * NS_ + n * S_ + sl;
            int f0 = fq * 64;
#pragma unroll 8
            for (int fi = 0; fi < 64; fi++) {
                float x = xp[(size_t)(f0 + fi) * NS_];
                float4 w1 = ((const float4*)wslf)[f0 + fi];
                float4 w2 = ((const float4*)wdlf)[f0 + fi];
                aS[0] += x * w1.x; aS[1] += x * w1.y; aS[2] += x * w1.z; aS[3] += x * w1.w;
                aD[0] += x * w2.x; aD[1] += x * w2.y; aD[2] += x * w2.z; aD[3] += x * w2.w;
            }
            float* rp = red1 + fq * 1728 + sl * 9;
#pragma unroll
            for (int h = 0; h < 4; h++) { rp[h] = aS[h]; rp[4 + h] = aD[h]; }
            __syncthreads();
            for (int c = t; c < 1536; c += NTHR) {
                int ss = c >> 3, k = c & 7;
                float vsum = red1[ss * 9 + k] + red1[1728 + ss * 9 + k];
                if (k < 4) {
                    int bh = b * 4 + k;
                    bool masked = (A[ss * 192 + n] == 0);   // mask = A[s, i=n]
                    float2 pr; pr.x = 0.f; pr.y = 0.f;
                    if (!masked) {
                        float pt = vsum + csh[k];
                        pr.x = EXP2(pt); pr.y = EXP2(0.2f * pt);
                    }
                    ((float2*)(ws + OFF_PE))[(size_t)bh * NS_ + n * 192 + ss] = pr;
                } else {
                    int h = k - 4, bh = b * 4 + h;
                    float dv = vsum + cdh[h];
                    ws[OFF_QD + (size_t)bh * NS_ + ss * 192 + n] = dv;   // [s][j]
                    ws[OFF_QT + (size_t)bh * NS_ + n * 192 + ss] = dv;   // [j][s]
                }
            }
        } else {
            // ---- X row sum, row u = b*128+f ----
            int u = v - 384;
            const float4* p = (const float4*)(X + (size_t)u * NS_);
            float acc = 0.f;
#pragma unroll
            for (int k = 0; k < 24; k++) {
                float4 x4 = p[t + k * NTHR];
                acc += (x4.x + x4.y) + (x4.z + x4.w);
            }
            for (int o = 32; o; o >>= 1) acc += __shfl_down(acc, o, 64);
            if ((t & 63) == 0) sg_red[t >> 6] = acc;
            __syncthreads();
            if (t == 0)
                ws[OFF_PART + u] = ((sg_red[0] + sg_red[1]) + (sg_red[2] + sg_red[3])) +
                                   (sg_red[4] + sg_red[5]);
        }
        markDone(&g_ctr[1], t);
    }
    waitDone(&g_ctr[1], TOTAL_A, t);

    // ================= Phase B queue: attention, (bh, it3), R=3 rows =================
    for (;;) {
        int v = grabItem(&g_ctr[2], &item_sh, t);
        if (v >= TOTAL_B) break;
        int bh = v & 7, it3 = v >> 3;
        const float2* PEp = (const float2*)(ws + OFF_PE) + (size_t)bh * NS_;
        const float*  QDf = ws + OFF_QD + (size_t)bh * NS_;
        const float*  QTf = ws + OFF_QT + (size_t)bh * NS_;
        if (t < 192) {
            float2 e0 = PEp[(it3 * 3 + 0) * 192 + t];
            float2 e1 = PEp[(it3 * 3 + 1) * 192 + t];
            float2 e2 = PEp[(it3 * 3 + 2) * 192 + t];
            peA4[t] = make_float4(e0.x, e0.y, e1.x, e1.y);
            peB2[t] = e2;
        }
        __syncthreads();
        {   // Pass A: Z[r][j] over s (halves of 96)
            int sq = t / 192, j = t - sq * 192;
            float z0 = 0.f, z1 = 0.f, z2 = 0.f;
#pragma unroll 8
            for (int s = sq * 96; s < sq * 96 + 96; s++) {
                float qv = QDf[s * 192 + j];
                float Q1 = EXP2(qv), Q2 = EXP2(0.2f * qv);
                float4 Ea = peA4[s];
                float2 Eb = peB2[s];
                z0 += fmaxf(Ea.x * Q1, Ea.y * Q2);
                z1 += fmaxf(Ea.z * Q1, Ea.w * Q2);
                z2 += fmaxf(Eb.x * Q1, Eb.y * Q2);
            }
            zpart[sq * 576 + 0 * 192 + j] = z0;
            zpart[sq * 576 + 1 * 192 + j] = z1;
            zpart[sq * 576 + 2 * 192 + j] = z2;
        }
        __syncthreads();
        for (int c = t; c < 576; c += NTHR) {
            int r = c / 192, j = c - r * 192;
            float Z = zpart[c] + zpart[576 + c];
            ((float*)zr4)[j * 4 + r] = (Z != 0.f) ? (1.f / Z) : 0.f;  // all-masked -> 0
        }
        __syncthreads();
        {   // Pass B: acc[r][s] over j (halves of 96)
            int jt = t / 192, s = t - jt * 192;
            float4 Ea = peA4[s];
            float2 Eb = peB2[s];
            float a0 = 0.f, a1 = 0.f, a2 = 0.f;
#pragma unroll 8
            for (int j = jt * 96; j < jt * 96 + 96; j++) {
                float g = QTf[j * 192 + s];
                float G1 = EXP2(g), G2 = EXP2(0.2f * g);
                float4 Z4 = zr4[j];
                a0 += fmaxf(Ea.x * G1, Ea.y * G2) * Z4.x;
                a1 += fmaxf(Ea.z * G1, Ea.w * G2) * Z4.y;
                a2 += fmaxf(Eb.x * G1, Eb.y * G2) * Z4.z;
            }
            accp[jt * 576 + 0 * 192 + s] = a0;
            accp[jt * 576 + 1 * 192 + s] = a1;
            accp[jt * 576 + 2 * 192 + s] = a2;
        }
        __syncthreads();
        for (int c = t; c < 576; c += NTHR) {
            int r = c / 192, s = c - r * 192;
            float acc = accp[c] + accp[576 + c];
            ws[OFF_ACC + (size_t)bh * NS_ + (it3 * 3 + r) * 192 + s] = acc;
        }
        markDone(&g_ctr[3], t);
    }
    waitDone(&g_ctr[3], TOTAL_B, t);

    // ================= Phase C queue: sum_g + linear expansion, (bh, d) =================
    for (;;) {
        int v = grabItem(&g_ctr[4], &item_sh, t);
        if (v >= TOTAL_C) break;
        int bh = v & 7, d = v >> 3;
        int b = bh >> 2, h = bh & 3;
        int cc = h * 64 + d;
        float psum = 0.f;
        if (t < 128)
            psum = (ws[OFF_PART + t] + ws[OFF_PART + 128 + t]) * W_lin[t * 256 + cc];
        for (int o = 32; o; o >>= 1) psum += __shfl_down(psum, o, 64);
        if ((t & 63) == 0) sg_red[t >> 6] = psum;
        __syncthreads();
        float sgd = sg_red[0] + sg_red[1] + 73728.f * b_lin[cc];
        const float4* ap = (const float4*)(ws + OFF_ACC + (size_t)bh * NS_);
        float4* op = (float4*)(out + ((size_t)(b * 256 + cc)) * NS_);
#pragma unroll
        for (int k = 0; k < 24; k++) {
            float4 a = ap[t + k * NTHR];
            op[t + k * NTHR] = make_float4(a.x * sgd, a.y * sgd, a.z * sgd, a.w * sgd);
        }
        __syncthreads();                    // protect sg_red before next item
    }

    // ---- exit protocol: last block out resets counters for the next replay ----
    if (t == 0) {
        int e = __hip_atomic_fetch_add(&g_ctr[5], 1, __ATOMIC_ACQ_REL, AGENT);
        if (e == NBLK - 1) {
#pragma unroll
            for (int i = 0; i < 8; i++)
                __hip_atomic_store(&g_ctr[i], 0, __ATOMIC_RELEASE, AGENT);
        }
    }
}

extern "C" void kernel_launch(void* const* d_in, const int* in_sizes, int n_in,
                              void* d_out, int out_size, void* d_ws, size_t ws_size,
                              hipStream_t stream) {
    const float* X      = (const float*)d_in[0];
    const int*   A      = (const int*)d_in[1];
    const float* W_lin  = (const float*)d_in[2];
    const float* b_lin  = (const float*)d_in[3];
    const float* W_attn = (const float*)d_in[4];
    const float* b_attn = (const float*)d_in[5];
    float* out = (float*)d_out;
    float* ws  = (float*)d_ws;

    kFused<<<NBLK, NTHR, 0, stream>>>(X, A, W_lin, b_lin, W_attn, b_attn, ws, out);
}

// Round 7
// 156.663 us; speedup vs baseline: 1.9819x; 1.9819x over previous
//
#include <hip/hip_runtime.h>
#include <math.h>

#define B_ 2
#define F_ 128
#define N_ 192
#define S_ 192
#define NS_ (N_ * S_)          // 36864
#define LOG2E 1.4426950408889634f

#if defined(__has_builtin)
#if __has_builtin(__builtin_amdgcn_exp2f)
#define EXP2(x) __builtin_amdgcn_exp2f(x)
#else
#define EXP2(x) exp2f(x)
#endif
#else
#define EXP2(x) exp2f(x)
#endif

// Workspace layout (float offsets)
#define OFF_WSRC 0             // [f*4+h] * LOG2E
#define OFF_WDST 512
#define OFF_CSRC 1024          // (c_src[h] + b_attn) * LOG2E
#define OFF_CDST 1028
#define OFF_SUMG 1040          // [h*64+d]
#define OFF_PART 1296          // [sq 4][b 2][f 128] xsum partials
// PE: float2 [bh][i][s] = (exp2(p), exp2(.2p)); masked -> (0,0).
// QD: float2 [bh][s][j] = (exp2(q), exp2(.2q));  QT: float2 [bh][j][s].
#define OFF_PE   2320                       // float2, 8*NS_*2 floats
#define OFF_QD   (OFF_PE + 8 * NS_ * 2)     // float2
#define OFF_QT   (OFF_QD + 8 * NS_ * 2)     // float2

// ---- kPre: blocks 0..1023 xsum partials; 1024: wsrc/wdst; 1025: csrc/cdst ----
__global__ __launch_bounds__(256) void kPre(const float* __restrict__ X,
                                            const float* __restrict__ W_lin,
                                            const float* __restrict__ b_lin,
                                            const float* __restrict__ W_attn,
                                            const float* __restrict__ b_attn,
                                            float* __restrict__ ws) {
    int blk = blockIdx.x, t = threadIdx.x;
    if (blk < 1024) {
        int sq = blk & 3, f = (blk >> 2) & 127, b = blk >> 9;
        const float4* p = (const float4*)(X + ((size_t)(b * F_ + f)) * NS_ + sq * 9216);
        float acc = 0.f;
#pragma unroll
        for (int k = 0; k < 9; k++) {
            float4 v = p[t + k * 256];
            acc += (v.x + v.y) + (v.z + v.w);
        }
        for (int o = 32; o; o >>= 1) acc += __shfl_down(acc, o, 64);
        __shared__ float red[4];
        if ((t & 63) == 0) red[t >> 6] = acc;
        __syncthreads();
        if (t == 0)
            ws[OFF_PART + sq * 256 + b * 128 + f] = (red[0] + red[1]) + (red[2] + red[3]);
    } else if (blk == 1024) {
        const float4* wa = (const float4*)W_attn;
        for (int c = t; c < 512; c += 256) {
            int f = c >> 2, h = c & 3;
            const float4* wl = (const float4*)(W_lin + f * 256 + h * 64);
            float as = 0.f, ad = 0.f;
#pragma unroll
            for (int q = 0; q < 16; q++) {
                float4 w = wl[q], a1 = wa[q], a2 = wa[16 + q];
                as += w.x * a1.x + w.y * a1.y + w.z * a1.z + w.w * a1.w;
                ad += w.x * a2.x + w.y * a2.y + w.z * a2.z + w.w * a2.w;
            }
            ws[OFF_WSRC + c] = as * LOG2E;
            ws[OFF_WDST + c] = ad * LOG2E;
        }
    } else {
        if (t < 4) {
            float c = 0.f;
            for (int d = 0; d < 64; d++) c += b_lin[t * 64 + d] * W_attn[d];
            ws[OFF_CSRC + t] = (c + b_attn[0]) * LOG2E;
        } else if (t < 8) {
            int h = t - 4;
            float c = 0.f;
            for (int d = 0; d < 64; d++) c += b_lin[h * 64 + d] * W_attn[64 + d];
            ws[OFF_CDST + h] = c * LOG2E;
        }
    }
}

// ---- kProj: blocks < 1152: (n, b, s-chunk of 64); block 1152: sum_g.
//      Epilogue stores PE / QD / QT exp-pairs (no trans left for kAttn). ----
__global__ __launch_bounds__(256) void kProj(const float* __restrict__ X,
                                             const int* __restrict__ A,
                                             const float* __restrict__ W_lin,
                                             const float* __restrict__ b_lin,
                                             float* __restrict__ ws) {
    __shared__ float4 wsl[128], wdl[128];
    __shared__ float red[4 * 64 * 9];     // [fq][lane][8 +1 pad]
    __shared__ float xs[128];
    __shared__ float wbuf[4096];
    int t = threadIdx.x, blk = blockIdx.x;
    if (blk < 1152) {
        int n = blk % 192, bsc = blk / 192;
        int b = bsc / 3, sc = bsc % 3;
        if (t < 128) {
            wsl[t] = ((const float4*)(ws + OFF_WSRC))[t];
            wdl[t] = ((const float4*)(ws + OFF_WDST))[t];
        }
        __syncthreads();
        int fq = t >> 6, lane = t & 63;
        int s = sc * 64 + lane;
        float aS[4] = {0, 0, 0, 0}, aD[4] = {0, 0, 0, 0};
        const float* xp = X + (size_t)(b * F_) * NS_ + n * S_ + s;
        int f0 = fq * 32;
#pragma unroll 8
        for (int fi = 0; fi < 32; fi++) {
            float x = xp[(size_t)(f0 + fi) * NS_];
            float4 w1 = wsl[f0 + fi], w2 = wdl[f0 + fi];
            aS[0] += x * w1.x; aS[1] += x * w1.y; aS[2] += x * w1.z; aS[3] += x * w1.w;
            aD[0] += x * w2.x; aD[1] += x * w2.y; aD[2] += x * w2.z; aD[3] += x * w2.w;
        }
        float* rp = red + t * 9;
#pragma unroll
        for (int h = 0; h < 4; h++) { rp[h] = aS[h]; rp[4 + h] = aD[h]; }
        __syncthreads();
        float2* PEp = (float2*)(ws + OFF_PE);
        float2* QD2 = (float2*)(ws + OFF_QD);
        float2* QT2 = (float2*)(ws + OFF_QT);
#pragma unroll
        for (int c = t; c < 512; c += 256) {
            int s_loc = c >> 3, k = c & 7;
            float v = red[s_loc * 9 + k] + red[(64 + s_loc) * 9 + k] +
                      red[(128 + s_loc) * 9 + k] + red[(192 + s_loc) * 9 + k];
            int ss = sc * 64 + s_loc;
            if (k < 4) {
                int bh = b * 4 + k;
                bool masked = (A[ss * 192 + n] == 0);   // mask = A[s, i=n]
                float2 pr; pr.x = 0.f; pr.y = 0.f;
                if (!masked) {
                    float pt = v + ws[OFF_CSRC + k];
                    pr.x = EXP2(pt); pr.y = EXP2(0.2f * pt);
                }
                PEp[(size_t)bh * NS_ + n * 192 + ss] = pr;
            } else {
                int h = k - 4, bh = b * 4 + h;
                float dv = v + ws[OFF_CDST + h];
                float2 qr; qr.x = EXP2(dv); qr.y = EXP2(0.2f * dv);
                QD2[(size_t)bh * NS_ + ss * 192 + n] = qr;   // [s][j]
                QT2[(size_t)bh * NS_ + n * 192 + ss] = qr;   // [j][s]
            }
        }
    } else {
        // sum_g[c] = sum_f xsum[f] * W_lin[f][c] + 73728 * b_lin[c]
        if (t < 128) {
            float v = 0.f;
#pragma unroll
            for (int q = 0; q < 8; q++) v += ws[OFF_PART + q * 128 + t];
            xs[t] = v;
        }
        float acc = 0.f;
        for (int ch = 0; ch < 8; ch++) {
            const float4* s4 = (const float4*)(W_lin + ch * 4096);
            __syncthreads();
#pragma unroll
            for (int k = 0; k < 4; k++) ((float4*)wbuf)[t + k * 256] = s4[t + k * 256];
            __syncthreads();
#pragma unroll
            for (int fi = 0; fi < 16; fi++) acc += xs[ch * 16 + fi] * wbuf[fi * 256 + t];
        }
        ws[OFF_SUMG + t] = acc + 73728.f * b_lin[t];
    }
}

// ---- kAttn v3: 768 blocks (bh = blk&7 XCD swizzle, R=2 rows), 384 thr.
//      float4 loads carry 2 cells' exp-pairs -> 4 cells (2j/2s x 2rows) = 16
//      VALU per 16B load; no transcendentals in the loops; E hoisted out of
//      the j-loop in pass B. Fused d-expansion epilogue (R3 showed splitting
//      it into a second kernel is net-negative). ----
__global__ __launch_bounds__(384) void kAttn(const float* __restrict__ ws,
                                             float* __restrict__ out) {
    int blk = blockIdx.x, t = threadIdx.x;
    int bh = blk & 7, iq = blk >> 3;        // iq 0..95, rows i = 2iq, 2iq+1
    int b = bh >> 2, h = bh & 3;
    __shared__ float4 pe4[192];             // [s] = (E1_r0,E2_r0,E1_r1,E2_r1)
    __shared__ float zpart[4 * 2 * 192];    // [sq][r][j]
    __shared__ float2 zr2[192];             // [j] = (zr_r0, zr_r1)
    __shared__ float accp[4 * 2 * 192];     // [jq][r][s]
    __shared__ float sg_sh[64];
    const float2* PEp = (const float2*)(ws + OFF_PE) + (size_t)bh * NS_;
    const float4* QD4 = (const float4*)(ws + OFF_QD) + (size_t)bh * (NS_ / 2);
    const float4* QT4 = (const float4*)(ws + OFF_QT) + (size_t)bh * (NS_ / 2);
    if (t < 64) sg_sh[t] = ws[OFF_SUMG + h * 64 + t];
    if (t < 192) {
        float2 e0 = PEp[(iq * 2) * 192 + t];
        float2 e1 = PEp[(iq * 2 + 1) * 192 + t];
        pe4[t] = make_float4(e0.x, e0.y, e1.x, e1.y);
    }
    __syncthreads();

    // Pass A: Z[r][j] = sum_s max(E1*Q1, E2*Q2). Thread = (sq 4, jp 96):
    // 48 s-iters, 2 adjacent j per float4 load, 2 rows from LDS broadcast.
    {
        int sq = t / 96, jp = t - sq * 96;
        float z00 = 0.f, z01 = 0.f, z10 = 0.f, z11 = 0.f;
#pragma unroll 8
        for (int s = sq * 48; s < sq * 48 + 48; s++) {
            float4 q = QD4[s * 96 + jp];    // (Q1,Q2)@j0, (Q1,Q2)@j1 — 16B coalesced
            float4 E = pe4[s];              // b128 broadcast
            z00 += fmaxf(E.x * q.x, E.y * q.y);
            z01 += fmaxf(E.x * q.z, E.y * q.w);
            z10 += fmaxf(E.z * q.x, E.w * q.y);
            z11 += fmaxf(E.z * q.z, E.w * q.w);
        }
        float* zp = zpart + sq * 384;
        zp[2 * jp] = z00; zp[2 * jp + 1] = z01;
        zp[192 + 2 * jp] = z10; zp[192 + 2 * jp + 1] = z11;
    }
    __syncthreads();
    {
        int r = t / 192, j = t - r * 192;
        float Z = zpart[r * 192 + j] + zpart[384 + r * 192 + j] +
                  zpart[768 + r * 192 + j] + zpart[1152 + r * 192 + j];
        ((float*)zr2)[j * 2 + r] = (Z != 0.f) ? (1.f / Z) : 0.f;  // all-masked -> 0
    }
    __syncthreads();

    // Pass B: acc[r][s] = sum_j max(E1*G1, E2*G2) * zr[r][j]. Thread = (jq 4,
    // sp 96): 48 j-iters, 2 adjacent s per float4 load, E hoisted (s fixed).
    {
        int jq = t / 96, sp = t - jq * 96;
        int s0 = 2 * sp, s1 = 2 * sp + 1;
        float4 E0 = pe4[s0], E1 = pe4[s1];  // once per pass (4-way conflict, amortized)
        float a00 = 0.f, a01 = 0.f, a10 = 0.f, a11 = 0.f;
#pragma unroll 8
        for (int j = jq * 48; j < jq * 48 + 48; j++) {
            float4 g = QT4[j * 96 + sp];    // (G1,G2)@s0, (G1,G2)@s1 — 16B coalesced
            float2 zr = zr2[j];             // b64 broadcast
            a00 += fmaxf(E0.x * g.x, E0.y * g.y) * zr.x;
            a01 += fmaxf(E1.x * g.z, E1.y * g.w) * zr.x;
            a10 += fmaxf(E0.z * g.x, E0.w * g.y) * zr.y;
            a11 += fmaxf(E1.z * g.z, E1.w * g.w) * zr.y;
        }
        float* ap = accp + jq * 384;
        ap[s0] = a00; ap[s1] = a01;
        ap[192 + s0] = a10; ap[192 + s1] = a11;
    }
    __syncthreads();

    // Fused epilogue: (r, s) cell -> 64 d-broadcast stores (256B coalesced each)
    {
        int r = t / 192, s = t - r * 192;
        float acc = accp[r * 192 + s] + accp[384 + r * 192 + s] +
                    accp[768 + r * 192 + s] + accp[1152 + r * 192 + s];
        int i = iq * 2 + r;
        float* op = out + (((size_t)(b * 256 + h * 64)) * 192 + i) * 192 + s;
#pragma unroll 8
        for (int d = 0; d < 64; d++)
            op[(size_t)d * NS_] = acc * sg_sh[d];
    }
}

extern "C" void kernel_launch(void* const* d_in, const int* in_sizes, int n_in,
                              void* d_out, int out_size, void* d_ws, size_t ws_size,
                              hipStream_t stream) {
    const float* X      = (const float*)d_in[0];
    const int*   A      = (const int*)d_in[1];
    const float* W_lin  = (const float*)d_in[2];
    const float* b_lin  = (const float*)d_in[3];
    const float* W_attn = (const float*)d_in[4];
    const float* b_attn = (const float*)d_in[5];
    float* out = (float*)d_out;
    float* ws  = (float*)d_ws;

    kPre<<<1026, 256, 0, stream>>>(X, W_lin, b_lin, W_attn, b_attn, ws);
    kProj<<<1153, 256, 0, stream>>>(X, A, W_lin, b_lin, ws);
    kAttn<<<768, 384, 0, stream>>>(ws, out);
}